// Round 1
// baseline (772.117 us; speedup 1.0000x reference)
//
#include <hip/hip_runtime.h>
#include <hip/hip_bf16.h>

// out = relu((x * drop_mask) @ weight @ support)
// Fused via associativity: W = weight @ support (128x128, precomputed per launch),
// then out = relu(xd @ W) -- a single memory-bound N=500k GEMM with K=N_out=128.

#define D 128

typedef __attribute__((ext_vector_type(8))) short short8;
typedef __attribute__((ext_vector_type(4))) float f32x4;

__device__ __forceinline__ short f2bf(float f) {
    union { __hip_bfloat16 h; short s; } u;
    u.h = __float2bfloat16(f);
    return u.s;
}

// --- Kernel 1: Wt[n][k] = (weight @ support)[k][n], bf16, into d_ws ---
__global__ void wprod_kernel(const float* __restrict__ weight,
                             const float* __restrict__ support,
                             unsigned short* __restrict__ wt) {
    __shared__ float wrow[D];
    const int i = blockIdx.x;
    const int j = threadIdx.x;
    wrow[j] = weight[i * D + j];
    __syncthreads();
    float acc = 0.f;
#pragma unroll 8
    for (int k = 0; k < D; ++k)
        acc = fmaf(wrow[k], support[k * D + j], acc);
    union { __hip_bfloat16 h; unsigned short s; } u;
    u.h = __float2bfloat16(acc);
    // store transposed: row n=j holds W[.][j] over k -> contiguous fragments
    wt[(size_t)j * D + i] = u.s;
}

// --- Kernel 2: out = relu(xd @ W) ---
// Per wave: 16-row slab. Software-pipelined: global loads for slab s+nwaves are
// issued before the MFMA+store phase of slab s (loads in flight under compute).
// MFMA operands swapped vs previous version => acc[r] = out[m][n*16+quad*4+r],
// giving contiguous f32x4 output stores (kills the 1.6x write amplification).
__global__ __launch_bounds__(256, 4) void gcn_fused(
    const float* __restrict__ x, const float* __restrict__ mask,
    const unsigned short* __restrict__ wt, float* __restrict__ out,
    int nslabs) {
    // 32 KB, XOR-swizzled 16B granules: granule g of row n lives at slot g^(n&7).
    // Read pattern (16 lanes, rows n*16+m, same granule) spreads across 8 bank
    // groups, 2 lanes each -> 2-way (free per m136).
    __shared__ __align__(16) unsigned short lw[D * D];

    const uint4* src = reinterpret_cast<const uint4*>(wt);
    for (int c = threadIdx.x; c < 2048; c += 256) {
        const int n = c >> 4;
        const int gs = (c & 15) ^ (n & 7);
        *reinterpret_cast<uint4*>(&lw[(n << 7) + (gs << 3)]) = src[c];
    }
    __syncthreads();

    const int lane = threadIdx.x & 63;
    const int m = lane & 15;    // A col-block lane / output slab-row
    const int quad = lane >> 4; // k-subchunk selector / C col-quad
    const int mx = m & 7;

    const int wave = (int)((blockIdx.x * blockDim.x + threadIdx.x) >> 6);
    const int nwaves = (int)((gridDim.x * blockDim.x) >> 6);

    const int rowoff = m * D + quad * 8;

    int s = wave;
    if (s >= nslabs) return;

    f32x4 vx[8], vm[8];

    // prologue: load slab s
    {
        const float* xr = x + (size_t)s * (16 * D) + rowoff;
        const float* mr = mask + (size_t)s * (16 * D) + rowoff;
#pragma unroll
        for (int kk = 0; kk < 4; ++kk) {
            vx[2 * kk]     = *reinterpret_cast<const f32x4*>(xr + kk * 32);
            vx[2 * kk + 1] = *reinterpret_cast<const f32x4*>(xr + kk * 32 + 4);
            vm[2 * kk]     = *reinterpret_cast<const f32x4*>(mr + kk * 32);
            vm[2 * kk + 1] = *reinterpret_cast<const f32x4*>(mr + kk * 32 + 4);
        }
    }

    while (true) {
        // convert current slab (data arrived during previous compute phase)
        short8 a[4];
#pragma unroll
        for (int kk = 0; kk < 4; ++kk) {
            f32x4 p0 = vx[2 * kk] * vm[2 * kk];
            f32x4 p1 = vx[2 * kk + 1] * vm[2 * kk + 1];
            short8 v;
            v[0] = f2bf(p0[0]); v[1] = f2bf(p0[1]);
            v[2] = f2bf(p0[2]); v[3] = f2bf(p0[3]);
            v[4] = f2bf(p1[0]); v[5] = f2bf(p1[1]);
            v[6] = f2bf(p1[2]); v[7] = f2bf(p1[3]);
            a[kk] = v;
        }

        // prefetch next slab into the (now-consumed) vx/vm registers;
        // these loads stay in flight across the MFMA+store phase below
        const int snext = s + nwaves;
        const bool more = snext < nslabs;
        if (more) {
            const float* xr = x + (size_t)snext * (16 * D) + rowoff;
            const float* mr = mask + (size_t)snext * (16 * D) + rowoff;
#pragma unroll
            for (int kk = 0; kk < 4; ++kk) {
                vx[2 * kk]     = *reinterpret_cast<const f32x4*>(xr + kk * 32);
                vx[2 * kk + 1] = *reinterpret_cast<const f32x4*>(xr + kk * 32 + 4);
                vm[2 * kk]     = *reinterpret_cast<const f32x4*>(mr + kk * 32);
                vm[2 * kk + 1] = *reinterpret_cast<const f32x4*>(mr + kk * 32 + 4);
            }
        }

        float* orow = out + (size_t)s * (16 * D) + m * D;
#pragma unroll
        for (int n = 0; n < 8; ++n) {
            f32x4 acc = {0.f, 0.f, 0.f, 0.f};
#pragma unroll
            for (int kk = 0; kk < 4; ++kk) {
                const short8 b = *reinterpret_cast<const short8*>(
                    &lw[(((n << 4) + m) << 7) + ((((kk << 2) + quad) ^ mx) << 3)]);
                // swapped operands: D' = D^T of the old mapping
                // => acc[r] = out[slabrow = m][col = n*16 + quad*4 + r]
                acc = __builtin_amdgcn_mfma_f32_16x16x32_bf16(b, a[kk], acc, 0, 0, 0);
            }
            f32x4 rv;
#pragma unroll
            for (int r = 0; r < 4; ++r) rv[r] = acc[r] > 0.f ? acc[r] : 0.f;
            // contiguous 16B store; adjacent n chunks merge into full lines in L2
            *reinterpret_cast<f32x4*>(&orow[(n << 4) + (quad << 2)]) = rv;
        }

        if (!more) break;
        s = snext;
    }
}

extern "C" void kernel_launch(void* const* d_in, const int* in_sizes, int n_in,
                              void* d_out, int out_size, void* d_ws, size_t ws_size,
                              hipStream_t stream) {
    const float* x = (const float*)d_in[0];
    const float* weight = (const float*)d_in[1];
    const float* support = (const float*)d_in[2];
    const float* mask = (const float*)d_in[3];
    float* out = (float*)d_out;
    unsigned short* wt = (unsigned short*)d_ws;  // 128*128 bf16 = 32 KB

    const int nrows = in_sizes[0] / D;   // 500000
    const int nslabs = nrows / 16;       // 31250 (exact)

    wprod_kernel<<<dim3(D), dim3(D), 0, stream>>>(weight, support, wt);
    // persistent: 4 blocks/CU x 256 CUs resident; each wave strides 7-8 slabs
    gcn_fused<<<dim3(1024), dim3(256), 0, stream>>>(x, mask, wt, out, nslabs);
}

// Round 2
// 764.647 us; speedup vs baseline: 1.0098x; 1.0098x over previous
//
#include <hip/hip_runtime.h>
#include <hip/hip_bf16.h>

// out = relu((x * drop_mask) @ weight @ support)
// Fused via associativity: W = weight @ support (128x128, precomputed per launch),
// then out = relu(xd @ W) -- a single memory-bound N=500k GEMM with K=N_out=128.

#define D 128

typedef __attribute__((ext_vector_type(8))) short short8;
typedef __attribute__((ext_vector_type(4))) float f32x4;

__device__ __forceinline__ short f2bf(float f) {
    union { __hip_bfloat16 h; short s; } u;
    u.h = __float2bfloat16(f);
    return u.s;
}

// --- Kernel 1: Wt[n][k] = (weight @ support)[k][n], bf16, into d_ws ---
__global__ void wprod_kernel(const float* __restrict__ weight,
                             const float* __restrict__ support,
                             unsigned short* __restrict__ wt) {
    __shared__ float wrow[D];
    const int i = blockIdx.x;
    const int j = threadIdx.x;
    wrow[j] = weight[i * D + j];
    __syncthreads();
    float acc = 0.f;
#pragma unroll 8
    for (int k = 0; k < D; ++k)
        acc = fmaf(wrow[k], support[k * D + j], acc);
    union { __hip_bfloat16 h; unsigned short s; } u;
    u.h = __float2bfloat16(acc);
    // store transposed: row n=j holds W[.][j] over k -> contiguous fragments
    wt[(size_t)j * D + i] = u.s;
}

// --- Kernel 2: out = relu(xd @ W) ---
// Latency-bound, so the lever is wave count: 512-thread blocks share one 32 KB
// Wt copy -> 4 blocks/CU x 8 waves = 32 waves/CU (occupancy cap), 2x round 0.
// launch_bounds(512,8) pins VGPR <= 64 (known sufficient) so occupancy holds.
// No manual pipelining: at a 64-VGPR budget the compiler either sinks or spills
// prefetch registers (round-1 post-mortem: +370 MB HBM traffic, same BW).
__global__ __launch_bounds__(512, 8) void gcn_fused(
    const float* __restrict__ x, const float* __restrict__ mask,
    const unsigned short* __restrict__ wt, float* __restrict__ out,
    int nslabs) {
    // 32 KB, XOR-swizzled 16B granules: granule g of row n lives at slot g^(n&7).
    // Read pattern (16 lanes, rows n*16+m, same granule) spreads across 8 bank
    // groups, 2 lanes each -> 2-way (free per m136).
    __shared__ __align__(16) unsigned short lw[D * D];

    const uint4* src = reinterpret_cast<const uint4*>(wt);
    for (int c = threadIdx.x; c < 2048; c += 512) {
        const int n = c >> 4;
        const int gs = (c & 15) ^ (n & 7);
        *reinterpret_cast<uint4*>(&lw[(n << 7) + (gs << 3)]) = src[c];
    }
    __syncthreads();

    const int lane = threadIdx.x & 63;
    const int m = lane & 15;    // output slab-row / Wt col within block
    const int quad = lane >> 4; // k-subchunk selector / C col-quad
    const int mx = m & 7;

    const int wave = (int)((blockIdx.x * blockDim.x + threadIdx.x) >> 6);
    const int nwaves = (int)((gridDim.x * blockDim.x) >> 6);

    const int rowoff = m * D + quad * 8;

    for (int s = wave; s < nslabs; s += nwaves) {
        const float* xr = x + (size_t)s * (16 * D) + rowoff;
        const float* mr = mask + (size_t)s * (16 * D) + rowoff;

        // Build A fragments for the full K=128: a[kk] covers k in [kk*32, kk*32+32)
        // x/mask are read-once streams: nontemporal keeps them evict-first in L2
        // so the cache stays available for output half-line write merging.
        short8 a[4];
#pragma unroll
        for (int kk = 0; kk < 4; ++kk) {
            f32x4 x0 = __builtin_nontemporal_load(
                reinterpret_cast<const f32x4*>(xr + kk * 32));
            f32x4 x1 = __builtin_nontemporal_load(
                reinterpret_cast<const f32x4*>(xr + kk * 32 + 4));
            f32x4 m0 = __builtin_nontemporal_load(
                reinterpret_cast<const f32x4*>(mr + kk * 32));
            f32x4 m1 = __builtin_nontemporal_load(
                reinterpret_cast<const f32x4*>(mr + kk * 32 + 4));
            f32x4 p0 = x0 * m0;
            f32x4 p1 = x1 * m1;
            short8 v;
            v[0] = f2bf(p0[0]); v[1] = f2bf(p0[1]);
            v[2] = f2bf(p0[2]); v[3] = f2bf(p0[3]);
            v[4] = f2bf(p1[0]); v[5] = f2bf(p1[1]);
            v[6] = f2bf(p1[2]); v[7] = f2bf(p1[3]);
            a[kk] = v;
        }

        float* orow = out + (size_t)s * (16 * D) + m * D;
#pragma unroll
        for (int n = 0; n < 8; ++n) {
            f32x4 acc = {0.f, 0.f, 0.f, 0.f};
#pragma unroll
            for (int kk = 0; kk < 4; ++kk) {
                const short8 b = *reinterpret_cast<const short8*>(
                    &lw[(((n << 4) + m) << 7) + ((((kk << 2) + quad) ^ mx) << 3)]);
                // swapped operands => acc[r] = out[row=m][col = n*16 + quad*4 + r]
                acc = __builtin_amdgcn_mfma_f32_16x16x32_bf16(b, a[kk], acc, 0, 0, 0);
            }
            f32x4 rv;
#pragma unroll
            for (int r = 0; r < 4; ++r) rv[r] = acc[r] > 0.f ? acc[r] : 0.f;
            // contiguous 16B store; adjacent-n chunks merge into full lines in L2
            *reinterpret_cast<f32x4*>(&orow[(n << 4) + (quad << 2)]) = rv;
        }
    }
}

extern "C" void kernel_launch(void* const* d_in, const int* in_sizes, int n_in,
                              void* d_out, int out_size, void* d_ws, size_t ws_size,
                              hipStream_t stream) {
    const float* x = (const float*)d_in[0];
    const float* weight = (const float*)d_in[1];
    const float* support = (const float*)d_in[2];
    const float* mask = (const float*)d_in[3];
    float* out = (float*)d_out;
    unsigned short* wt = (unsigned short*)d_ws;  // 128*128 bf16 = 32 KB

    const int nrows = in_sizes[0] / D;   // 500000
    const int nslabs = nrows / 16;       // 31250 (exact)

    wprod_kernel<<<dim3(D), dim3(D), 0, stream>>>(weight, support, wt);
    // persistent: 4 blocks/CU x 512 threads = 32 waves/CU resident (100% cap)
    gcn_fused<<<dim3(1024), dim3(512), 0, stream>>>(x, mask, wt, out, nslabs);
}